// Round 10
// baseline (467.233 us; speedup 1.0000x reference)
//
#include <hip/hip_runtime.h>
#include <hip/hip_fp16.h>

#define T_STEPS 2048
#define BATCH   256

// ---------- DPP helper for zx kernel (validated rounds 2-5) ----------
template<int CTRL>
__device__ __forceinline__ float dppf(float x) {
  int i = __float_as_int(x);
  int r = __builtin_amdgcn_update_dpp(i, i, CTRL, 0xF, 0xF, false);
  return __int_as_float(r);
}
#define DPP_X1 0xB1   // quad_perm {1,0,3,2}: lane^1
#define PIN(x) asm volatile("" : "+v"(x))
#define L2E 1.442695040888963f

// ---------- Phase 1: ZX[b][t][unit*4+gate] = x@Wx + b (fp16, packed dword stores) ----------
// (unchanged from round 9 — validated; launched TWICE this round as a timing probe:
//  zx_time = delta_total(r10-r9) - delta_lstm(r10-r9), since lstm time is visible in counters)
__global__ __launch_bounds__(256, 4) void zx_kernel(const float* __restrict__ x,
                                                    const float* __restrict__ Wx,
                                                    const float* __restrict__ bias,
                                                    unsigned* __restrict__ zx) {
  __shared__ float sWx[1024];
  __shared__ float sb[32];
  {
    int t = (int)threadIdx.x;
    for (int i = t; i < 1024; i += 256) sWx[i] = Wx[i];
    if (t < 32) sb[t] = bias[t];
  }
  __syncthreads();

  int wave = (blockIdx.x * 256 + (int)threadIdx.x) >> 6;
  int lane = (int)threadIdx.x & 63;
  int l    = lane & 31;
  int r    = lane >> 5;
  int j    = (l & 3) * 8 + (l >> 2);

  float wxc[32];
#pragma unroll
  for (int d = 0; d < 32; ++d) wxc[d] = sWx[d * 32 + j];
  float bj = sb[j];

  int base = wave * 64;
  for (int it = 0; it < 32; ++it) {
#pragma unroll
    for (int d = 0; d < 32; ++d) PIN(wxc[d]);
    PIN(bj);
    int row = base + (it << 1) + r;
    const float4* xr = (const float4*)(x + (size_t)row * 32);
    float a = bj, b2 = 0.0f;
#pragma unroll
    for (int qq = 0; qq < 8; ++qq) {
      float4 v = xr[qq];
      a  = fmaf(v.x, wxc[4*qq+0], a);
      b2 = fmaf(v.y, wxc[4*qq+1], b2);
      a  = fmaf(v.z, wxc[4*qq+2], a);
      b2 = fmaf(v.w, wxc[4*qq+3], b2);
    }
    float v  = a + b2;
    float pv = dppf<DPP_X1>(v);
    float lo = (l & 1) ? pv : v;
    float hi = (l & 1) ? v  : pv;
    union { _Float16 h2[2]; unsigned u; } pk;
    pk.h2[0] = (_Float16)lo;
    pk.h2[1] = (_Float16)hi;
    zx[(size_t)row * 16 + (l >> 1)] = pk.u;
  }
}

// ---------- Phase 2: hand-scheduled asm recurrence, 16 lanes per batch ----------
// (byte-identical to round 9 — 246.5 us, absmax 0.0039)

#define GATHER_DOTS \
  "v_mov_b32_dpp %[tC], %[h] quad_perm:[2,3,0,1] row_mask:0xf bank_mask:0xf\n\t" \
  "v_mov_b32_dpp %[tD], %[h] row_half_mirror row_mask:0xf bank_mask:0xf\n\t" \
  "v_mov_b32_dpp %[tE], %[h] row_mirror row_mask:0xf bank_mask:0xf\n\t" \
  "v_fmac_f32 %[tA], %[h], %[wA0]\n\t" \
  "v_fmac_f32 %[tB], %[h], %[wB0]\n\t" \
  "v_mov_b32_dpp %[tF], %[tD] quad_perm:[2,3,0,1] row_mask:0xf bank_mask:0xf\n\t" \
  "v_mul_f32 %[tG], %[tC], %[wA1]\n\t" \
  "v_mul_f32 %[tH], %[tC], %[wB1]\n\t" \
  "v_mov_b32_dpp %[tC], %[tE] quad_perm:[2,3,0,1] row_mask:0xf bank_mask:0xf\n\t" \
  "v_fmac_f32 %[tG], %[tD], %[wA3]\n\t" \
  "v_fmac_f32 %[tH], %[tD], %[wB3]\n\t" \
  "v_mov_b32_dpp %[tD], %[tE] row_half_mirror row_mask:0xf bank_mask:0xf\n\t" \
  "v_fmac_f32 %[tA], %[tF], %[wA2]\n\t" \
  "v_fmac_f32 %[tB], %[tF], %[wB2]\n\t" \
  "v_fmac_f32 %[tG], %[tE], %[wA7]\n\t" \
  "v_fmac_f32 %[tH], %[tE], %[wB7]\n\t" \
  "v_mov_b32_dpp %[tE], %[tD] quad_perm:[2,3,0,1] row_mask:0xf bank_mask:0xf\n\t" \
  "v_fmac_f32 %[tA], %[tC], %[wA6]\n\t" \
  "v_fmac_f32 %[tB], %[tC], %[wB6]\n\t" \
  "v_fmac_f32 %[tA], %[tD], %[wA4]\n\t" \
  "v_fmac_f32 %[tB], %[tD], %[wB4]\n\t" \
  "v_fmac_f32 %[tG], %[tE], %[wA5]\n\t" \
  "v_fmac_f32 %[tH], %[tE], %[wB5]\n\t"

#define ACTPART \
  "v_add_f32 %[tA], %[tA], %[tG]\n\t" \
  "v_add_f32 %[tB], %[tB], %[tH]\n\t" \
  "v_mul_f32 %[tC], %[cAc], %[tA]\n\t" \
  "v_mul_f32 %[tD], 0xbfb8aa3b, %[tB]\n\t" \
  "v_exp_f32 %[tC], %[tC]\n\t" \
  "v_exp_f32 %[tD], %[tD]\n\t" \
  "s_nop 0\n\t" \
  "v_add_f32 %[tC], 1.0, %[tC]\n\t" \
  "v_add_f32 %[tD], 1.0, %[tD]\n\t" \
  "v_rcp_f32 %[tC], %[tC]\n\t" \
  "v_rcp_f32 %[tD], %[tD]\n\t" \
  "s_nop 1\n\t" \
  "v_mov_b32_dpp %[tE], %[tD] quad_perm:[1,0,3,2] row_mask:0xf bank_mask:0xf\n\t" \
  "v_mov_b32_dpp %[tF], %[tC] quad_perm:[1,0,3,2] row_mask:0xf bank_mask:0xf\n\t" \
  "v_cndmask_b32 %[tG], %[tD], %[tE], vcc\n\t" \
  "v_cndmask_b32 %[tH], %[tE], %[tD], vcc\n\t" \
  "v_cndmask_b32 %[tE], %[tC], %[tF], vcc\n\t" \
  "v_mul_f32 %[tF], %[tC], %[tF]\n\t" \
  "v_fma_f32 %[tF], 2.0, %[tF], -%[tE]\n\t" \
  "v_fma_f32 %[c], %[tG], %[c], %[tF]\n\t" \
  "v_mul_f32 %[tA], 0xc038aa3b, %[c]\n\t" \
  "v_exp_f32 %[tA], %[tA]\n\t" \
  "s_nop 0\n\t" \
  "v_add_f32 %[tA], 1.0, %[tA]\n\t" \
  "v_rcp_f32 %[tA], %[tA]\n\t" \
  "s_nop 0\n\t" \
  "v_mul_f32 %[tB], %[tH], %[tA]\n\t" \
  "v_fma_f32 %[h], 2.0, %[tB], -%[tH]\n\t"

#define LSTEP(K, PF, SO) \
  "s_waitcnt vmcnt(7)\n\t" \
  "v_cvt_f32_f16 %[tA], %[b" #K "]\n\t" \
  "v_lshrrev_b32 %[tB], 16, %[b" #K "]\n\t" \
  "v_cvt_f32_f16 %[tB], %[tB]\n\t" \
  "global_load_dword %[b" #K "], %[zoff], %[zb] offset:" #PF "\n\t" \
  GATHER_DOTS ACTPART \
  "global_store_dword %[ooff], %[h], %[ob] offset:" #SO "\n\t"

#define ESTEP(K, SO) \
  "s_waitcnt vmcnt(7)\n\t" \
  "v_cvt_f32_f16 %[tA], %[b" #K "]\n\t" \
  "v_lshrrev_b32 %[tB], 16, %[b" #K "]\n\t" \
  "v_cvt_f32_f16 %[tB], %[tB]\n\t" \
  GATHER_DOTS ACTPART \
  "global_store_dword %[ooff], %[h], %[ob] offset:" #SO "\n\t"

__global__ __launch_bounds__(64, 1) void lstm_kernel(const __half* __restrict__ zx,
                                                     const float* __restrict__ h0,
                                                     const float* __restrict__ c0,
                                                     const float* __restrict__ Wh,
                                                     float* __restrict__ out) {
  __shared__ float sWh[256];
  int lane = (int)threadIdx.x;
  for (int i = lane; i < 256; i += 64) sWh[i] = Wh[i];
  __syncthreads();

  int b = blockIdx.x * 4 + (lane >> 4);
  int q = lane & 15;
  int u = q >> 1;
  int p = q & 1;

  float wA[8], wB[8];
#pragma unroll
  for (int m = 0; m < 8; ++m) {
    int jrow = u ^ m;
    wA[m] = sWh[jrow * 32 + (2 * p) * 8 + u];
    wB[m] = sWh[jrow * 32 + (2 * p + 1) * 8 + u];
  }
  float cAc = p ? (-2.0f * L2E) : (-L2E);

  float h = h0[b * 8 + u];
  float c = c0[b * 8 + u];

  const unsigned* zp = (const unsigned*)zx;
  unsigned zoff = (unsigned)(b * T_STEPS * 64 + u * 8 + p * 4);   // byte offset
  unsigned ooff = (unsigned)(b * T_STEPS * 32 + u * 4);           // byte offset

  unsigned b0 = zp[(zoff >> 2) + 0 * 16];
  unsigned b1 = zp[(zoff >> 2) + 1 * 16];
  unsigned b2 = zp[(zoff >> 2) + 2 * 16];
  unsigned b3 = zp[(zoff >> 2) + 3 * 16];
  unsigned b4 = zp[(zoff >> 2) + 4 * 16];
  unsigned b5 = zp[(zoff >> 2) + 5 * 16];
  unsigned b6 = zp[(zoff >> 2) + 6 * 16];
  unsigned b7 = zp[(zoff >> 2) + 7 * 16];

  float tA, tB, tC, tD, tE, tF, tG, tH;
  int cnt;

  asm volatile(
    // vcc = (lane & 1) == 1  (p-mask for cndmask selects)
    "v_mbcnt_lo_u32_b32 %[tA], -1, 0\n\t"
    "v_mbcnt_hi_u32_b32 %[tA], -1, %[tA]\n\t"
    "v_and_b32 %[tA], 1, %[tA]\n\t"
    "v_cmp_eq_u32 vcc, 1, %[tA]\n\t"
    "s_mov_b32 %[cnt], 255\n\t"
    "LSTM_LOOP%=:\n\t"
    LSTEP(0, 512, 0)
    LSTEP(1, 576, 32)
    LSTEP(2, 640, 64)
    LSTEP(3, 704, 96)
    LSTEP(4, 768, 128)
    LSTEP(5, 832, 160)
    LSTEP(6, 896, 192)
    LSTEP(7, 960, 224)
    "v_add_u32 %[zoff], 0x200, %[zoff]\n\t"
    "v_add_u32 %[ooff], 0x100, %[ooff]\n\t"
    "s_sub_u32 %[cnt], %[cnt], 1\n\t"
    "s_cmp_lg_u32 %[cnt], 0\n\t"
    "s_cbranch_scc1 LSTM_LOOP%=\n\t"
    // epilogue: last 8 steps, no prefetch
    ESTEP(0, 0)
    ESTEP(1, 32)
    ESTEP(2, 64)
    ESTEP(3, 96)
    ESTEP(4, 128)
    ESTEP(5, 160)
    ESTEP(6, 192)
    ESTEP(7, 224)
    : [h]"+v"(h), [c]"+v"(c), [zoff]"+v"(zoff), [ooff]"+v"(ooff),
      [b0]"+v"(b0), [b1]"+v"(b1), [b2]"+v"(b2), [b3]"+v"(b3),
      [b4]"+v"(b4), [b5]"+v"(b5), [b6]"+v"(b6), [b7]"+v"(b7),
      [tA]"=&v"(tA), [tB]"=&v"(tB), [tC]"=&v"(tC), [tD]"=&v"(tD),
      [tE]"=&v"(tE), [tF]"=&v"(tF), [tG]"=&v"(tG), [tH]"=&v"(tH),
      [cnt]"=&s"(cnt)
    : [wA0]"v"(wA[0]), [wA1]"v"(wA[1]), [wA2]"v"(wA[2]), [wA3]"v"(wA[3]),
      [wA4]"v"(wA[4]), [wA5]"v"(wA[5]), [wA6]"v"(wA[6]), [wA7]"v"(wA[7]),
      [wB0]"v"(wB[0]), [wB1]"v"(wB[1]), [wB2]"v"(wB[2]), [wB3]"v"(wB[3]),
      [wB4]"v"(wB[4]), [wB5]"v"(wB[5]), [wB6]"v"(wB[6]), [wB7]"v"(wB[7]),
      [cAc]"v"(cAc), [zb]"s"(zp), [ob]"s"(out)
    : "vcc", "scc", "memory");

  out[(size_t)BATCH * T_STEPS * 8 +             b * 8 + u] = h;
  out[(size_t)BATCH * T_STEPS * 8 + BATCH * 8 + b * 8 + u] = c;
}

extern "C" void kernel_launch(void* const* d_in, const int* in_sizes, int n_in,
                              void* d_out, int out_size, void* d_ws, size_t ws_size,
                              hipStream_t stream) {
  const float* x    = (const float*)d_in[0];
  const float* h0   = (const float*)d_in[1];
  const float* c0   = (const float*)d_in[2];
  const float* Wx   = (const float*)d_in[3];
  const float* Wh   = (const float*)d_in[4];
  const float* bias = (const float*)d_in[5];
  float* out = (float*)d_out;

  // zx launched TWICE (idempotent): timing probe to split zx vs harness overhead.
  // zx_time = (total_r10 - total_r9) - (lstm_r10 - lstm_r9)
  zx_kernel<<<2048, 256, 0, stream>>>(x, Wx, bias, (unsigned*)d_ws);
  zx_kernel<<<2048, 256, 0, stream>>>(x, Wx, bias, (unsigned*)d_ws);
  lstm_kernel<<<BATCH / 4, 64, 0, stream>>>((const __half*)d_ws, h0, c0, Wh, out);
}